// Round 2
// baseline (4895.848 us; speedup 1.0000x reference)
//
#include <hip/hip_runtime.h>
#include <hip/hip_bf16.h>

// GNN classifier: 4x ChebConv(K=10) + global attention pooling + 2 dense.
// N=100k nodes, E=1.6M edges, G=16 graphs, HID=64 f32.
// R1 changes vs R0:
//  - edge-weight CSR: csr[e] = (src, nrm[src]*nrm[dst]) as int2 (no per-edge nrm gather)
//  - fused prop+GEMM kernel (gather -> LDS tile -> GEMM accumulate); saves X re-read
//    and 36 launches; skips the dead X_{K-1} global write per layer
//  - feat consumed in-place as X_0 (no initial D2D copy)

#define NN 100000
#define NE 1600000
#define NG 16
#define HID 64
#define KORD 10
#define NLAYERS 4
#define NCLASSES 3

constexpr int SCAN_TILE = 1024;
constexpr int NTILES = (NN + SCAN_TILE - 1) / SCAN_TILE; // 98

// ---------------- CSR build ----------------

__global__ void degree_kernel(const int* __restrict__ dst, int* __restrict__ deg) {
  int i = blockIdx.x * blockDim.x + threadIdx.x;
  if (i < NE) atomicAdd(&deg[dst[i]], 1);
}

__global__ void norm_kernel(const int* __restrict__ deg, float* __restrict__ nrm) {
  int i = blockIdx.x * blockDim.x + threadIdx.x;
  if (i < NN) {
    int d = deg[i];
    if (d < 1) d = 1;
    nrm[i] = 1.0f / sqrtf((float)d);
  }
}

__global__ void tile_reduce(const int* __restrict__ deg, int* __restrict__ partial) {
  __shared__ int sh[SCAN_TILE];
  int i = blockIdx.x * SCAN_TILE + threadIdx.x;
  sh[threadIdx.x] = (i < NN) ? deg[i] : 0;
  __syncthreads();
  for (int off = SCAN_TILE / 2; off > 0; off >>= 1) {
    if (threadIdx.x < off) sh[threadIdx.x] += sh[threadIdx.x + off];
    __syncthreads();
  }
  if (threadIdx.x == 0) partial[blockIdx.x] = sh[0];
}

__global__ void scan_partials(int* __restrict__ partial, int* __restrict__ rs) {
  if (threadIdx.x == 0) {
    int acc = 0;
    for (int b = 0; b < NTILES; ++b) { int v = partial[b]; partial[b] = acc; acc += v; }
    rs[NN] = acc; // == NE
  }
}

__global__ void tile_scan(const int* __restrict__ deg, const int* __restrict__ partial,
                          int* __restrict__ rs) {
  __shared__ int sh[SCAN_TILE];
  int tid = threadIdx.x;
  int i = blockIdx.x * SCAN_TILE + tid;
  int v = (i < NN) ? deg[i] : 0;
  sh[tid] = v;
  __syncthreads();
  for (int off = 1; off < SCAN_TILE; off <<= 1) {
    int t = (tid >= off) ? sh[tid - off] : 0;
    __syncthreads();
    sh[tid] += t;
    __syncthreads();
  }
  if (i < NN) rs[i] = partial[blockIdx.x] + sh[tid] - v; // exclusive
}

__global__ void fill_kernel(const int* __restrict__ src, const int* __restrict__ dst,
                            const int* __restrict__ rs, const float* __restrict__ nrm,
                            int* __restrict__ cursor, int2* __restrict__ csr) {
  int i = blockIdx.x * blockDim.x + threadIdx.x;
  if (i < NE) {
    int d = dst[i];
    int s = src[i];
    int pos = rs[d] + atomicAdd(&cursor[d], 1);
    csr[pos] = make_int2(s, __float_as_int(nrm[s] * nrm[d]));
  }
}

// ---------------- fused Chebyshev step: X_k = scale*A_hat X_{k-1} [- X_{k-2}] ; ACC (op)= X_k @ W
// Block = 64 nodes, 256 threads. Phase 1: wave-per-16-nodes gather (lane = feature),
// tile -> LDS (+ global X_k unless last k). Phase 2: 4x4-microtile GEMM from LDS,
// W read from global (16KB, L1-resident). MODE 1: ACC += ; MODE 2: ACC = relu(ACC + .)
// xout may alias sub (element-wise same-thread read-then-write).

template <int MODE, bool SUB, bool WRITE_X>
__global__ __launch_bounds__(256) void prop_gemm(
    const float* __restrict__ xin, const float* __restrict__ sub,
    const int* __restrict__ rs, const int2* __restrict__ csr,
    const float* __restrict__ W, float* __restrict__ xout,
    float* __restrict__ OUT, float scale) {
  __shared__ float Xs[64][68]; // +4 pad: breaks pow2 stride for GEMM-phase reads
  int t = threadIdx.x;
  int base = blockIdx.x * 64;
  int wv = t >> 6, lane = t & 63;

#pragma unroll 1
  for (int i = 0; i < 16; ++i) {
    int nl = (wv << 4) + i;
    int gn = base + nl;
    float acc = 0.0f;
    if (gn < NN) {
      int beg = rs[gn], end = rs[gn + 1];
      int e = beg;
      for (; e + 1 < end; e += 2) {
        int2 p0 = csr[e], p1 = csr[e + 1];
        acc = fmaf(xin[p0.x * 64 + lane], __int_as_float(p0.y), acc);
        acc = fmaf(xin[p1.x * 64 + lane], __int_as_float(p1.y), acc);
      }
      if (e < end) {
        int2 p = csr[e];
        acc = fmaf(xin[p.x * 64 + lane], __int_as_float(p.y), acc);
      }
    }
    float r = scale * acc;
    if (SUB && gn < NN) r -= sub[gn * 64 + lane];
    Xs[nl][lane] = r;
    if (WRITE_X && gn < NN) xout[gn * 64 + lane] = r;
  }
  __syncthreads();

  int j0 = (t & 15) << 2;  // output-dim group
  int n0 = (t >> 4) << 2;  // node group
  float acc4[4][4] = {};
#pragma unroll 8
  for (int d = 0; d < 64; ++d) {
    float4 wv4 = *(const float4*)&W[d * 64 + j0];
    float xv[4];
#pragma unroll
    for (int i = 0; i < 4; ++i) xv[i] = Xs[n0 + i][d];
#pragma unroll
    for (int i = 0; i < 4; ++i) {
      acc4[i][0] = fmaf(xv[i], wv4.x, acc4[i][0]);
      acc4[i][1] = fmaf(xv[i], wv4.y, acc4[i][1]);
      acc4[i][2] = fmaf(xv[i], wv4.z, acc4[i][2]);
      acc4[i][3] = fmaf(xv[i], wv4.w, acc4[i][3]);
    }
  }

#pragma unroll
  for (int i = 0; i < 4; ++i) {
    int gn = base + n0 + i;
    if (gn >= NN) continue;
    float4* o = (float4*)&OUT[gn * 64 + j0];
    float4 c = *o;
    float4 r;
    if (MODE == 1) {
      r.x = acc4[i][0] + c.x; r.y = acc4[i][1] + c.y;
      r.z = acc4[i][2] + c.z; r.w = acc4[i][3] + c.w;
    } else {
      r.x = fmaxf(acc4[i][0] + c.x, 0.0f);
      r.y = fmaxf(acc4[i][1] + c.y, 0.0f);
      r.z = fmaxf(acc4[i][2] + c.z, 0.0f);
      r.w = fmaxf(acc4[i][3] + c.w, 0.0f);
    }
    *o = r;
  }
}

// ---------------- k=0 GEMM: ACC = X @ W + b ----------------

__global__ __launch_bounds__(256) void gemm64_init(const float* __restrict__ X,
                                                   const float* __restrict__ W,
                                                   const float* __restrict__ bias,
                                                   float* __restrict__ OUT) {
  __shared__ float Xs[64][68];
  int t = threadIdx.x;
  int base = blockIdx.x * 64;

  int nl = t >> 4;
  int d4 = (t & 15) << 2;
#pragma unroll
  for (int i = 0; i < 4; ++i) {
    int n = nl + (i << 4);
    int gn = base + n;
    float4 v;
    if (gn < NN) v = *(const float4*)&X[gn * 64 + d4];
    else { v.x = v.y = v.z = v.w = 0.0f; }
    *(float4*)&Xs[n][d4] = v;
  }
  __syncthreads();

  int j0 = (t & 15) << 2;
  int n0 = (t >> 4) << 2;
  float acc[4][4] = {};
#pragma unroll 8
  for (int d = 0; d < 64; ++d) {
    float4 wv = *(const float4*)&W[d * 64 + j0];
    float xv[4];
#pragma unroll
    for (int i = 0; i < 4; ++i) xv[i] = Xs[n0 + i][d];
#pragma unroll
    for (int i = 0; i < 4; ++i) {
      acc[i][0] = fmaf(xv[i], wv.x, acc[i][0]);
      acc[i][1] = fmaf(xv[i], wv.y, acc[i][1]);
      acc[i][2] = fmaf(xv[i], wv.z, acc[i][2]);
      acc[i][3] = fmaf(xv[i], wv.w, acc[i][3]);
    }
  }
  float4 b = *(const float4*)&bias[j0];
#pragma unroll
  for (int i = 0; i < 4; ++i) {
    int gn = base + n0 + i;
    if (gn >= NN) continue;
    float4 r;
    r.x = acc[i][0] + b.x; r.y = acc[i][1] + b.y;
    r.z = acc[i][2] + b.z; r.w = acc[i][3] + b.w;
    *(float4*)&OUT[gn * 64 + j0] = r;
  }
}

// ---------------- pooling ----------------

__device__ __forceinline__ unsigned enc_f32(float f) {
  unsigned u = __float_as_uint(f);
  return (u & 0x80000000u) ? ~u : (u | 0x80000000u);
}
__device__ __forceinline__ float dec_f32(unsigned v) {
  return (v & 0x80000000u) ? __uint_as_float(v ^ 0x80000000u) : __uint_as_float(~v);
}

__global__ void gate_kernel(const float* __restrict__ h, const float* __restrict__ Wg,
                            const float* __restrict__ bg, const int* __restrict__ seg,
                            float* __restrict__ gate, unsigned* __restrict__ gmax) {
  __shared__ float wg_s[64];
  __shared__ unsigned gmax_l[NG];
  int t = threadIdx.x;
  if (t < 64) wg_s[t] = Wg[t];
  if (t < NG) gmax_l[t] = 0u;
  __syncthreads();
  int n = blockIdx.x * 256 + t;
  if (n < NN) {
    float acc = bg[0];
    const float4* hx = (const float4*)&h[n * 64];
#pragma unroll
    for (int d4 = 0; d4 < 16; ++d4) {
      float4 v = hx[d4];
      acc += v.x * wg_s[d4 * 4] + v.y * wg_s[d4 * 4 + 1] +
             v.z * wg_s[d4 * 4 + 2] + v.w * wg_s[d4 * 4 + 3];
    }
    gate[n] = acc;
    atomicMax(&gmax_l[seg[n]], enc_f32(acc));
  }
  __syncthreads();
  if (t < NG && gmax_l[t]) atomicMax(&gmax[t], gmax_l[t]);
}

__global__ void ek_kernel(float* __restrict__ gate, const int* __restrict__ seg,
                          const unsigned* __restrict__ gmax, float* __restrict__ z) {
  __shared__ float zl[NG];
  int t = threadIdx.x;
  if (t < NG) zl[t] = 0.0f;
  __syncthreads();
  int n = blockIdx.x * 256 + t;
  if (n < NN) {
    int g = seg[n];
    float e = expf(gate[n] - dec_f32(gmax[g]));
    gate[n] = e;
    atomicAdd(&zl[g], e);
  }
  __syncthreads();
  if (t < NG && zl[t] != 0.0f) atomicAdd(&z[t], zl[t]);
}

constexpr int CHUNKS = 1024;
constexpr int CHUNK_LEN = (NN + CHUNKS - 1) / CHUNKS; // 98

__global__ void hg_kernel(const float* __restrict__ h, const float* __restrict__ e,
                          const int* __restrict__ seg, const float* __restrict__ z,
                          float* __restrict__ hg) {
  int t = threadIdx.x;
  int d = t & 63;
  int chunk = blockIdx.x * 4 + (t >> 6);
  int n0 = chunk * CHUNK_LEN;
  if (n0 >= NN) return;
  int n1 = min(n0 + CHUNK_LEN, NN);
  float acc = 0.0f;
  int gc = seg[n0];
  for (int n = n0; n < n1; ++n) {
    int g = seg[n];
    if (g != gc) {
      atomicAdd(&hg[gc * 64 + d], acc / z[gc]);
      acc = 0.0f;
      gc = g;
    }
    acc = fmaf(h[n * 64 + d], e[n], acc);
  }
  atomicAdd(&hg[gc * 64 + d], acc / z[gc]);
}

__global__ void final_kernel(const float* __restrict__ hg, const float* __restrict__ W1,
                             const float* __restrict__ b1, const float* __restrict__ W2,
                             const float* __restrict__ b2, float* __restrict__ out) {
  __shared__ float hgs[NG][64];
  __shared__ float a2[NG][64];
  int t = threadIdx.x;
  for (int i = t; i < NG * 64; i += 256) hgs[i >> 6][i & 63] = hg[i];
  __syncthreads();
  int j = t & 63;
  int g0 = t >> 6; // 0..3
#pragma unroll
  for (int i = 0; i < 4; ++i) {
    int g = g0 * 4 + i;
    float acc = b1[j];
    for (int d = 0; d < 64; ++d) acc = fmaf(hgs[g][d], W1[d * 64 + j], acc);
    a2[g][j] = acc; // no relu (matches reference)
  }
  __syncthreads();
  if (t < NG * NCLASSES) {
    int g = t / NCLASSES, c = t % NCLASSES;
    float acc = b2[c];
    for (int d = 0; d < 64; ++d) acc = fmaf(a2[g][d], W2[d * NCLASSES + c], acc);
    out[g * NCLASSES + c] = acc;
  }
}

// ---------------- host ----------------

extern "C" void kernel_launch(void* const* d_in, const int* in_sizes, int n_in,
                              void* d_out, int out_size, void* d_ws, size_t ws_size,
                              hipStream_t stream) {
  const float* feat = (const float*)d_in[0];
  const float* Wc   = (const float*)d_in[1];
  const float* bc   = (const float*)d_in[2];
  const float* Wg   = (const float*)d_in[3];
  const float* bg   = (const float*)d_in[4];
  const float* W1   = (const float*)d_in[5];
  const float* b1   = (const float*)d_in[6];
  const float* W2   = (const float*)d_in[7];
  const float* b2   = (const float*)d_in[8];
  const int*   src  = (const int*)d_in[9];
  const int*   dst  = (const int*)d_in[10];
  const int*   seg  = (const int*)d_in[11];
  float* out = (float*)d_out;

  // workspace carve (4B units; all major buffers 16B-aligned by construction)
  float* fw = (float*)d_ws;
  size_t off = 0;
  float* w0 = fw + off; off += (size_t)NN * 64;   // 6.4M
  float* w1 = fw + off; off += (size_t)NN * 64;
  float* w2 = fw + off; off += (size_t)NN * 64;
  float* nrm  = fw + off; off += NN;
  float* gate = fw + off; off += NN;
  float* zbuf = fw + off; off += 16;
  unsigned* gmax = (unsigned*)(fw + off); off += 16;
  float* hg = fw + off; off += NG * 64;
  // off*4 here is a multiple of 16 -> int2 csr is 8B-aligned
  int2* csr = (int2*)(fw + off); off += (size_t)NE * 2;
  int* deg     = (int*)(fw + off);
  int* cursor  = deg + NN;
  int* rs      = cursor + NN;
  int* partial = rs + NN + 1;
  size_t need = (off + 2 * (size_t)NN + (NN + 1) + (NTILES + 1)) * 4;
  if (ws_size < need) return; // insufficient workspace -> loud validation failure

  hipMemsetAsync(deg, 0, NN * sizeof(int), stream);
  hipMemsetAsync(cursor, 0, NN * sizeof(int), stream);
  hipMemsetAsync(gmax, 0, NG * sizeof(unsigned), stream);
  hipMemsetAsync(zbuf, 0, NG * sizeof(float), stream);
  hipMemsetAsync(hg, 0, NG * 64 * sizeof(float), stream);

  degree_kernel<<<(NE + 255) / 256, 256, 0, stream>>>(dst, deg);
  norm_kernel<<<(NN + 255) / 256, 256, 0, stream>>>(deg, nrm);
  tile_reduce<<<NTILES, SCAN_TILE, 0, stream>>>(deg, partial);
  scan_partials<<<1, 64, 0, stream>>>(partial, rs);
  tile_scan<<<NTILES, SCAN_TILE, 0, stream>>>(deg, partial, rs);
  fill_kernel<<<(NE + 255) / 256, 256, 0, stream>>>(src, dst, rs, nrm, cursor, csr);

  const int GB = (NN + 63) / 64; // 1563 blocks of 64 nodes

  // Buffer plan (3 node buffers + read-only feat):
  //  L0: x0=feat, A=w0, B=w1, acc=w2 -> h=w2
  //  L1: x0=w2,   A=w0, B=w2, acc=w1 -> h=w1
  //  L2: x0=w1,   A=w0, B=w1, acc=w2 -> h=w2
  //  L3: x0=w2,   A=w0, B=w2, acc=w1 -> h=w1
  const float* h = feat;
  for (int layer = 0; layer < NLAYERS; ++layer) {
    const float* Wl = Wc + (size_t)layer * KORD * 64 * 64;
    const float* bl = bc + (size_t)layer * 64;
    const float* x0 = h;
    float* A = w0;
    float* B = (layer == 0) ? w1 : (float*)x0;           // X2 overwrites h_in (elem-wise)
    float* acc = (layer == 0) ? w2 : ((x0 == w2) ? w1 : w2);

    // k=0: acc = X0 @ W0 + b
    gemm64_init<<<GB, 256, 0, stream>>>(x0, Wl, bl, acc);
    // k=1: X1 = -A_hat X0 ; acc += X1 @ W1
    prop_gemm<1, false, true><<<GB, 256, 0, stream>>>(x0, nullptr, rs, csr,
                                                      Wl + 4096, A, acc, -1.0f);
    // k=2: X2 = -2 A_hat X1 - X0 ; acc += X2 @ W2
    prop_gemm<1, true, true><<<GB, 256, 0, stream>>>(A, x0, rs, csr,
                                                     Wl + 2 * 4096, B, acc, -2.0f);
    // k=3..K-1: X_k = -2 A_hat X_{k-1} - X_{k-2}, overwrite X_{k-2} in place
    float* p = A; // X_{k-2}
    float* q = B; // X_{k-1}
    for (int k = 3; k < KORD; ++k) {
      if (k == KORD - 1) {
        prop_gemm<2, true, false><<<GB, 256, 0, stream>>>(q, p, rs, csr,
                                                          Wl + (size_t)k * 4096, p, acc, -2.0f);
      } else {
        prop_gemm<1, true, true><<<GB, 256, 0, stream>>>(q, p, rs, csr,
                                                         Wl + (size_t)k * 4096, p, acc, -2.0f);
        float* tmp = p; p = q; q = tmp;
      }
    }
    h = acc; // relu applied in the last prop_gemm (MODE 2)
  }

  gate_kernel<<<(NN + 255) / 256, 256, 0, stream>>>(h, Wg, bg, seg, gate, gmax);
  ek_kernel<<<(NN + 255) / 256, 256, 0, stream>>>(gate, seg, gmax, zbuf);
  hg_kernel<<<256, 256, 0, stream>>>(h, gate, seg, zbuf, hg);
  final_kernel<<<1, 256, 0, stream>>>(hg, W1, b1, W2, b2, out);
}

// Round 3
// 4646.657 us; speedup vs baseline: 1.0536x; 1.0536x over previous
//
#include <hip/hip_runtime.h>
#include <hip/hip_bf16.h>

// GNN classifier: 4x ChebConv(K=10) + global attention pooling + 2 dense.
// N=100k nodes, E=1.6M edges, G=16 graphs, HID=64 f32.
// R3 changes vs R2 (prop_gemm was 97% of runtime, latency-bound: VGPR=32,
// VALUBusy=23%, 2.0 TB/s apparent):
//  - gather edge loop unrolled x4 (4 independent x-row loads in flight)
//  - CSR stores pre-scaled row offset (src*64) -> no per-edge address mul
//  - non-temporal csr loads (read-once stream; don't evict x rows from L2)
//  - non-temporal xout stores (not re-read in-kernel)

#define NN 100000
#define NE 1600000
#define NG 16
#define HID 64
#define KORD 10
#define NLAYERS 4
#define NCLASSES 3

constexpr int SCAN_TILE = 1024;
constexpr int NTILES = (NN + SCAN_TILE - 1) / SCAN_TILE; // 98

// ---------------- CSR build ----------------

__global__ void degree_kernel(const int* __restrict__ dst, int* __restrict__ deg) {
  int i = blockIdx.x * blockDim.x + threadIdx.x;
  if (i < NE) atomicAdd(&deg[dst[i]], 1);
}

__global__ void norm_kernel(const int* __restrict__ deg, float* __restrict__ nrm) {
  int i = blockIdx.x * blockDim.x + threadIdx.x;
  if (i < NN) {
    int d = deg[i];
    if (d < 1) d = 1;
    nrm[i] = 1.0f / sqrtf((float)d);
  }
}

__global__ void tile_reduce(const int* __restrict__ deg, int* __restrict__ partial) {
  __shared__ int sh[SCAN_TILE];
  int i = blockIdx.x * SCAN_TILE + threadIdx.x;
  sh[threadIdx.x] = (i < NN) ? deg[i] : 0;
  __syncthreads();
  for (int off = SCAN_TILE / 2; off > 0; off >>= 1) {
    if (threadIdx.x < off) sh[threadIdx.x] += sh[threadIdx.x + off];
    __syncthreads();
  }
  if (threadIdx.x == 0) partial[blockIdx.x] = sh[0];
}

__global__ void scan_partials(int* __restrict__ partial, int* __restrict__ rs) {
  if (threadIdx.x == 0) {
    int acc = 0;
    for (int b = 0; b < NTILES; ++b) { int v = partial[b]; partial[b] = acc; acc += v; }
    rs[NN] = acc; // == NE
  }
}

__global__ void tile_scan(const int* __restrict__ deg, const int* __restrict__ partial,
                          int* __restrict__ rs) {
  __shared__ int sh[SCAN_TILE];
  int tid = threadIdx.x;
  int i = blockIdx.x * SCAN_TILE + tid;
  int v = (i < NN) ? deg[i] : 0;
  sh[tid] = v;
  __syncthreads();
  for (int off = 1; off < SCAN_TILE; off <<= 1) {
    int t = (tid >= off) ? sh[tid - off] : 0;
    __syncthreads();
    sh[tid] += t;
    __syncthreads();
  }
  if (i < NN) rs[i] = partial[blockIdx.x] + sh[tid] - v; // exclusive
}

// csr entry = (src*64, bitcast(nrm[src]*nrm[dst]))
__global__ void fill_kernel(const int* __restrict__ src, const int* __restrict__ dst,
                            const int* __restrict__ rs, const float* __restrict__ nrm,
                            int* __restrict__ cursor, int2* __restrict__ csr) {
  int i = blockIdx.x * blockDim.x + threadIdx.x;
  if (i < NE) {
    int d = dst[i];
    int s = src[i];
    int pos = rs[d] + atomicAdd(&cursor[d], 1);
    csr[pos] = make_int2(s << 6, __float_as_int(nrm[s] * nrm[d]));
  }
}

// ---------------- fused Chebyshev step ----------------
// X_k = scale*A_hat X_{k-1} [- X_{k-2}] ; ACC (op)= X_k @ W
// Block = 64 nodes, 256 threads. Phase 1: wave-per-16-nodes gather (lane = feature),
// 4-unrolled edge loop, tile -> LDS (+ NT global X_k unless last k).
// Phase 2: 4x4-microtile GEMM from LDS, W from global (L1-resident).
// MODE 1: ACC += ; MODE 2: ACC = relu(ACC + .). xout may alias sub.

template <int MODE, bool SUB, bool WRITE_X>
__global__ __launch_bounds__(256) void prop_gemm(
    const float* __restrict__ xin, const float* __restrict__ sub,
    const int* __restrict__ rs, const int2* __restrict__ csr,
    const float* __restrict__ W, float* __restrict__ xout,
    float* __restrict__ OUT, float scale) {
  __shared__ float Xs[64][68]; // +4 pad: breaks pow2 stride for GEMM-phase reads
  int t = threadIdx.x;
  int base = blockIdx.x * 64;
  int wv = t >> 6, lane = t & 63;

#pragma unroll 1
  for (int i = 0; i < 16; ++i) {
    int nl = (wv << 4) + i;
    int gn = base + nl;
    float r = 0.0f;
    if (gn < NN) {
      int beg = rs[gn], end = rs[gn + 1];
      float a0 = 0.f, a1 = 0.f, a2 = 0.f, a3 = 0.f;
      int e = beg;
      for (; e + 3 < end; e += 4) {
        long long q0 = __builtin_nontemporal_load((const long long*)&csr[e]);
        long long q1 = __builtin_nontemporal_load((const long long*)&csr[e + 1]);
        long long q2 = __builtin_nontemporal_load((const long long*)&csr[e + 2]);
        long long q3 = __builtin_nontemporal_load((const long long*)&csr[e + 3]);
        float v0 = xin[(int)q0 + lane];
        float v1 = xin[(int)q1 + lane];
        float v2 = xin[(int)q2 + lane];
        float v3 = xin[(int)q3 + lane];
        a0 = fmaf(v0, __int_as_float((int)(q0 >> 32)), a0);
        a1 = fmaf(v1, __int_as_float((int)(q1 >> 32)), a1);
        a2 = fmaf(v2, __int_as_float((int)(q2 >> 32)), a2);
        a3 = fmaf(v3, __int_as_float((int)(q3 >> 32)), a3);
      }
      for (; e < end; ++e) {
        long long q = __builtin_nontemporal_load((const long long*)&csr[e]);
        a0 = fmaf(xin[(int)q + lane], __int_as_float((int)(q >> 32)), a0);
      }
      r = scale * ((a0 + a1) + (a2 + a3));
      if (SUB) r -= sub[gn * 64 + lane];
    }
    Xs[nl][lane] = r;
    if (WRITE_X && gn < NN) __builtin_nontemporal_store(r, &xout[gn * 64 + lane]);
  }
  __syncthreads();

  int j0 = (t & 15) << 2;  // output-dim group
  int n0 = (t >> 4) << 2;  // node group
  float acc4[4][4] = {};
#pragma unroll 8
  for (int d = 0; d < 64; ++d) {
    float4 wv4 = *(const float4*)&W[d * 64 + j0];
    float xv[4];
#pragma unroll
    for (int i = 0; i < 4; ++i) xv[i] = Xs[n0 + i][d];
#pragma unroll
    for (int i = 0; i < 4; ++i) {
      acc4[i][0] = fmaf(xv[i], wv4.x, acc4[i][0]);
      acc4[i][1] = fmaf(xv[i], wv4.y, acc4[i][1]);
      acc4[i][2] = fmaf(xv[i], wv4.z, acc4[i][2]);
      acc4[i][3] = fmaf(xv[i], wv4.w, acc4[i][3]);
    }
  }

#pragma unroll
  for (int i = 0; i < 4; ++i) {
    int gn = base + n0 + i;
    if (gn >= NN) continue;
    float4* o = (float4*)&OUT[gn * 64 + j0];
    float4 c = *o;
    float4 r;
    if (MODE == 1) {
      r.x = acc4[i][0] + c.x; r.y = acc4[i][1] + c.y;
      r.z = acc4[i][2] + c.z; r.w = acc4[i][3] + c.w;
    } else {
      r.x = fmaxf(acc4[i][0] + c.x, 0.0f);
      r.y = fmaxf(acc4[i][1] + c.y, 0.0f);
      r.z = fmaxf(acc4[i][2] + c.z, 0.0f);
      r.w = fmaxf(acc4[i][3] + c.w, 0.0f);
    }
    *o = r;
  }
}

// ---------------- k=0 GEMM: ACC = X @ W + b ----------------

__global__ __launch_bounds__(256) void gemm64_init(const float* __restrict__ X,
                                                   const float* __restrict__ W,
                                                   const float* __restrict__ bias,
                                                   float* __restrict__ OUT) {
  __shared__ float Xs[64][68];
  int t = threadIdx.x;
  int base = blockIdx.x * 64;

  int nl = t >> 4;
  int d4 = (t & 15) << 2;
#pragma unroll
  for (int i = 0; i < 4; ++i) {
    int n = nl + (i << 4);
    int gn = base + n;
    float4 v;
    if (gn < NN) v = *(const float4*)&X[gn * 64 + d4];
    else { v.x = v.y = v.z = v.w = 0.0f; }
    *(float4*)&Xs[n][d4] = v;
  }
  __syncthreads();

  int j0 = (t & 15) << 2;
  int n0 = (t >> 4) << 2;
  float acc[4][4] = {};
#pragma unroll 8
  for (int d = 0; d < 64; ++d) {
    float4 wv = *(const float4*)&W[d * 64 + j0];
    float xv[4];
#pragma unroll
    for (int i = 0; i < 4; ++i) xv[i] = Xs[n0 + i][d];
#pragma unroll
    for (int i = 0; i < 4; ++i) {
      acc[i][0] = fmaf(xv[i], wv.x, acc[i][0]);
      acc[i][1] = fmaf(xv[i], wv.y, acc[i][1]);
      acc[i][2] = fmaf(xv[i], wv.z, acc[i][2]);
      acc[i][3] = fmaf(xv[i], wv.w, acc[i][3]);
    }
  }
  float4 b = *(const float4*)&bias[j0];
#pragma unroll
  for (int i = 0; i < 4; ++i) {
    int gn = base + n0 + i;
    if (gn >= NN) continue;
    float4 r;
    r.x = acc[i][0] + b.x; r.y = acc[i][1] + b.y;
    r.z = acc[i][2] + b.z; r.w = acc[i][3] + b.w;
    *(float4*)&OUT[gn * 64 + j0] = r;
  }
}

// ---------------- pooling ----------------

__device__ __forceinline__ unsigned enc_f32(float f) {
  unsigned u = __float_as_uint(f);
  return (u & 0x80000000u) ? ~u : (u | 0x80000000u);
}
__device__ __forceinline__ float dec_f32(unsigned v) {
  return (v & 0x80000000u) ? __uint_as_float(v ^ 0x80000000u) : __uint_as_float(~v);
}

__global__ void gate_kernel(const float* __restrict__ h, const float* __restrict__ Wg,
                            const float* __restrict__ bg, const int* __restrict__ seg,
                            float* __restrict__ gate, unsigned* __restrict__ gmax) {
  __shared__ float wg_s[64];
  __shared__ unsigned gmax_l[NG];
  int t = threadIdx.x;
  if (t < 64) wg_s[t] = Wg[t];
  if (t < NG) gmax_l[t] = 0u;
  __syncthreads();
  int n = blockIdx.x * 256 + t;
  if (n < NN) {
    float acc = bg[0];
    const float4* hx = (const float4*)&h[n * 64];
#pragma unroll
    for (int d4 = 0; d4 < 16; ++d4) {
      float4 v = hx[d4];
      acc += v.x * wg_s[d4 * 4] + v.y * wg_s[d4 * 4 + 1] +
             v.z * wg_s[d4 * 4 + 2] + v.w * wg_s[d4 * 4 + 3];
    }
    gate[n] = acc;
    atomicMax(&gmax_l[seg[n]], enc_f32(acc));
  }
  __syncthreads();
  if (t < NG && gmax_l[t]) atomicMax(&gmax[t], gmax_l[t]);
}

__global__ void ek_kernel(float* __restrict__ gate, const int* __restrict__ seg,
                          const unsigned* __restrict__ gmax, float* __restrict__ z) {
  __shared__ float zl[NG];
  int t = threadIdx.x;
  if (t < NG) zl[t] = 0.0f;
  __syncthreads();
  int n = blockIdx.x * 256 + t;
  if (n < NN) {
    int g = seg[n];
    float e = expf(gate[n] - dec_f32(gmax[g]));
    gate[n] = e;
    atomicAdd(&zl[g], e);
  }
  __syncthreads();
  if (t < NG && zl[t] != 0.0f) atomicAdd(&z[t], zl[t]);
}

constexpr int CHUNKS = 1024;
constexpr int CHUNK_LEN = (NN + CHUNKS - 1) / CHUNKS; // 98

__global__ void hg_kernel(const float* __restrict__ h, const float* __restrict__ e,
                          const int* __restrict__ seg, const float* __restrict__ z,
                          float* __restrict__ hg) {
  int t = threadIdx.x;
  int d = t & 63;
  int chunk = blockIdx.x * 4 + (t >> 6);
  int n0 = chunk * CHUNK_LEN;
  if (n0 >= NN) return;
  int n1 = min(n0 + CHUNK_LEN, NN);
  float acc = 0.0f;
  int gc = seg[n0];
  for (int n = n0; n < n1; ++n) {
    int g = seg[n];
    if (g != gc) {
      atomicAdd(&hg[gc * 64 + d], acc / z[gc]);
      acc = 0.0f;
      gc = g;
    }
    acc = fmaf(h[n * 64 + d], e[n], acc);
  }
  atomicAdd(&hg[gc * 64 + d], acc / z[gc]);
}

__global__ void final_kernel(const float* __restrict__ hg, const float* __restrict__ W1,
                             const float* __restrict__ b1, const float* __restrict__ W2,
                             const float* __restrict__ b2, float* __restrict__ out) {
  __shared__ float hgs[NG][64];
  __shared__ float a2[NG][64];
  int t = threadIdx.x;
  for (int i = t; i < NG * 64; i += 256) hgs[i >> 6][i & 63] = hg[i];
  __syncthreads();
  int j = t & 63;
  int g0 = t >> 6; // 0..3
#pragma unroll
  for (int i = 0; i < 4; ++i) {
    int g = g0 * 4 + i;
    float acc = b1[j];
    for (int d = 0; d < 64; ++d) acc = fmaf(hgs[g][d], W1[d * 64 + j], acc);
    a2[g][j] = acc; // no relu (matches reference)
  }
  __syncthreads();
  if (t < NG * NCLASSES) {
    int g = t / NCLASSES, c = t % NCLASSES;
    float acc = b2[c];
    for (int d = 0; d < 64; ++d) acc = fmaf(a2[g][d], W2[d * NCLASSES + c], acc);
    out[g * NCLASSES + c] = acc;
  }
}

// ---------------- host ----------------

extern "C" void kernel_launch(void* const* d_in, const int* in_sizes, int n_in,
                              void* d_out, int out_size, void* d_ws, size_t ws_size,
                              hipStream_t stream) {
  const float* feat = (const float*)d_in[0];
  const float* Wc   = (const float*)d_in[1];
  const float* bc   = (const float*)d_in[2];
  const float* Wg   = (const float*)d_in[3];
  const float* bg   = (const float*)d_in[4];
  const float* W1   = (const float*)d_in[5];
  const float* b1   = (const float*)d_in[6];
  const float* W2   = (const float*)d_in[7];
  const float* b2   = (const float*)d_in[8];
  const int*   src  = (const int*)d_in[9];
  const int*   dst  = (const int*)d_in[10];
  const int*   seg  = (const int*)d_in[11];
  float* out = (float*)d_out;

  // workspace carve (4B units; all major buffers 16B-aligned by construction)
  float* fw = (float*)d_ws;
  size_t off = 0;
  float* w0 = fw + off; off += (size_t)NN * 64;   // 6.4M
  float* w1 = fw + off; off += (size_t)NN * 64;
  float* w2 = fw + off; off += (size_t)NN * 64;
  float* nrm  = fw + off; off += NN;
  float* gate = fw + off; off += NN;
  float* zbuf = fw + off; off += 16;
  unsigned* gmax = (unsigned*)(fw + off); off += 16;
  float* hg = fw + off; off += NG * 64;
  // off*4 here is a multiple of 16 -> int2 csr is 8B-aligned
  int2* csr = (int2*)(fw + off); off += (size_t)NE * 2;
  int* deg     = (int*)(fw + off);
  int* cursor  = deg + NN;
  int* rs      = cursor + NN;
  int* partial = rs + NN + 1;
  size_t need = (off + 2 * (size_t)NN + (NN + 1) + (NTILES + 1)) * 4;
  if (ws_size < need) return; // insufficient workspace -> loud validation failure

  hipMemsetAsync(deg, 0, NN * sizeof(int), stream);
  hipMemsetAsync(cursor, 0, NN * sizeof(int), stream);
  hipMemsetAsync(gmax, 0, NG * sizeof(unsigned), stream);
  hipMemsetAsync(zbuf, 0, NG * sizeof(float), stream);
  hipMemsetAsync(hg, 0, NG * 64 * sizeof(float), stream);

  degree_kernel<<<(NE + 255) / 256, 256, 0, stream>>>(dst, deg);
  norm_kernel<<<(NN + 255) / 256, 256, 0, stream>>>(deg, nrm);
  tile_reduce<<<NTILES, SCAN_TILE, 0, stream>>>(deg, partial);
  scan_partials<<<1, 64, 0, stream>>>(partial, rs);
  tile_scan<<<NTILES, SCAN_TILE, 0, stream>>>(deg, partial, rs);
  fill_kernel<<<(NE + 255) / 256, 256, 0, stream>>>(src, dst, rs, nrm, cursor, csr);

  const int GB = (NN + 63) / 64; // 1563 blocks of 64 nodes

  // Buffer plan (3 node buffers + read-only feat):
  //  L0: x0=feat, A=w0, B=w1, acc=w2 -> h=w2
  //  L1: x0=w2,   A=w0, B=w2, acc=w1 -> h=w1
  //  L2: x0=w1,   A=w0, B=w1, acc=w2 -> h=w2
  //  L3: x0=w2,   A=w0, B=w2, acc=w1 -> h=w1
  const float* h = feat;
  for (int layer = 0; layer < NLAYERS; ++layer) {
    const float* Wl = Wc + (size_t)layer * KORD * 64 * 64;
    const float* bl = bc + (size_t)layer * 64;
    const float* x0 = h;
    float* A = w0;
    float* B = (layer == 0) ? w1 : (float*)x0;           // X2 overwrites h_in (elem-wise)
    float* acc = (layer == 0) ? w2 : ((x0 == w2) ? w1 : w2);

    // k=0: acc = X0 @ W0 + b
    gemm64_init<<<GB, 256, 0, stream>>>(x0, Wl, bl, acc);
    // k=1: X1 = -A_hat X0 ; acc += X1 @ W1
    prop_gemm<1, false, true><<<GB, 256, 0, stream>>>(x0, nullptr, rs, csr,
                                                      Wl + 4096, A, acc, -1.0f);
    // k=2: X2 = -2 A_hat X1 - X0 ; acc += X2 @ W2
    prop_gemm<1, true, true><<<GB, 256, 0, stream>>>(A, x0, rs, csr,
                                                     Wl + 2 * 4096, B, acc, -2.0f);
    // k=3..K-1: X_k = -2 A_hat X_{k-1} - X_{k-2}, overwrite X_{k-2} in place
    float* p = A; // X_{k-2}
    float* q = B; // X_{k-1}
    for (int k = 3; k < KORD; ++k) {
      if (k == KORD - 1) {
        prop_gemm<2, true, false><<<GB, 256, 0, stream>>>(q, p, rs, csr,
                                                          Wl + (size_t)k * 4096, p, acc, -2.0f);
      } else {
        prop_gemm<1, true, true><<<GB, 256, 0, stream>>>(q, p, rs, csr,
                                                         Wl + (size_t)k * 4096, p, acc, -2.0f);
        float* tmp = p; p = q; q = tmp;
      }
    }
    h = acc; // relu applied in the last prop_gemm (MODE 2)
  }

  gate_kernel<<<(NN + 255) / 256, 256, 0, stream>>>(h, Wg, bg, seg, gate, gmax);
  ek_kernel<<<(NN + 255) / 256, 256, 0, stream>>>(gate, seg, gmax, zbuf);
  hg_kernel<<<256, 256, 0, stream>>>(h, gate, seg, zbuf, hg);
  final_kernel<<<1, 256, 0, stream>>>(hg, W1, b1, W2, b2, out);
}

// Round 6
// 3384.790 us; speedup vs baseline: 1.4464x; 1.3728x over previous
//
#include <hip/hip_runtime.h>
#include <hip/hip_bf16.h>

// GNN classifier: 4x ChebConv(K=10) + global attention pooling + 2 dense.
// N=100k nodes, E=1.6M edges, G=16 graphs, HID=64 f32.
// R6 = R5 resubmission (GPU unavailable in R5; kernel never ran).
// Design (prop_gemm ~97% of runtime; diagnosis: L2-miss-path BW ceiling
// ~2.2 TB/s + wave-uniform csr broadcast loads serializing the chain):
//  - 32-node / 128-thread blocks: 3125 blocks (12.2/CU), NN%32==0 -> no tails
//  - per-node csr packet: ONE coalesced 512B NT load + __shfl register broadcast
//    (replaces 16 serial 8B broadcast loads); next node's packet prefetched
//  - 8-deep independent x-gather unroll (x loads are the only VMEM in the loop)
//  - NT discipline: csr/sub/OUT/xout all non-temporal -> L2 reserved for x rows

#define NN 100000
#define NE 1600000
#define NG 16
#define HID 64
#define KORD 10
#define NLAYERS 4
#define NCLASSES 3

typedef float f4_t __attribute__((ext_vector_type(4)));

constexpr int SCAN_TILE = 1024;
constexpr int NTILES = (NN + SCAN_TILE - 1) / SCAN_TILE; // 98

// ---------------- CSR build ----------------

__global__ void degree_kernel(const int* __restrict__ dst, int* __restrict__ deg) {
  int i = blockIdx.x * blockDim.x + threadIdx.x;
  if (i < NE) atomicAdd(&deg[dst[i]], 1);
}

__global__ void norm_kernel(const int* __restrict__ deg, float* __restrict__ nrm) {
  int i = blockIdx.x * blockDim.x + threadIdx.x;
  if (i < NN) {
    int d = deg[i];
    if (d < 1) d = 1;
    nrm[i] = 1.0f / sqrtf((float)d);
  }
}

__global__ void tile_reduce(const int* __restrict__ deg, int* __restrict__ partial) {
  __shared__ int sh[SCAN_TILE];
  int i = blockIdx.x * SCAN_TILE + threadIdx.x;
  sh[threadIdx.x] = (i < NN) ? deg[i] : 0;
  __syncthreads();
  for (int off = SCAN_TILE / 2; off > 0; off >>= 1) {
    if (threadIdx.x < off) sh[threadIdx.x] += sh[threadIdx.x + off];
    __syncthreads();
  }
  if (threadIdx.x == 0) partial[blockIdx.x] = sh[0];
}

__global__ void scan_partials(int* __restrict__ partial, int* __restrict__ rs) {
  if (threadIdx.x == 0) {
    int acc = 0;
    for (int b = 0; b < NTILES; ++b) { int v = partial[b]; partial[b] = acc; acc += v; }
    rs[NN] = acc; // == NE
  }
}

__global__ void tile_scan(const int* __restrict__ deg, const int* __restrict__ partial,
                          int* __restrict__ rs) {
  __shared__ int sh[SCAN_TILE];
  int tid = threadIdx.x;
  int i = blockIdx.x * SCAN_TILE + tid;
  int v = (i < NN) ? deg[i] : 0;
  sh[tid] = v;
  __syncthreads();
  for (int off = 1; off < SCAN_TILE; off <<= 1) {
    int t = (tid >= off) ? sh[tid - off] : 0;
    __syncthreads();
    sh[tid] += t;
    __syncthreads();
  }
  if (i < NN) rs[i] = partial[blockIdx.x] + sh[tid] - v; // exclusive
}

// csr entry = (src*64, bitcast(nrm[src]*nrm[dst])) packed little-endian in 8B
__global__ void fill_kernel(const int* __restrict__ src, const int* __restrict__ dst,
                            const int* __restrict__ rs, const float* __restrict__ nrm,
                            int* __restrict__ cursor, int2* __restrict__ csr) {
  int i = blockIdx.x * blockDim.x + threadIdx.x;
  if (i < NE) {
    int d = dst[i];
    int s = src[i];
    int pos = rs[d] + atomicAdd(&cursor[d], 1);
    csr[pos] = make_int2(s << 6, __float_as_int(nrm[s] * nrm[d]));
  }
}

// ---------------- fused Chebyshev step ----------------
// X_k = scale*A_hat X_{k-1} [- X_{k-2}] ; ACC (op)= X_k @ W
// 128 threads / 32 nodes per block. Gather: wave handles 16 nodes; per node one
// coalesced NT csr-packet load (lane e -> edge e), broadcast via __shfl, 8-deep
// independent x gathers. GEMM: 4x4 microtile from LDS, W global (L1-resident).
// MODE 1: ACC += ; MODE 2: ACC = relu(ACC + .). xout may alias sub.

template <int MODE, bool SUB, bool WRITE_X>
__global__ __launch_bounds__(128, 8) void prop_gemm(
    const float* __restrict__ xin, const float* __restrict__ sub,
    const int* __restrict__ rs, const long long* __restrict__ csr,
    const float* __restrict__ W, float* __restrict__ xout,
    float* __restrict__ OUT, float scale) {
  __shared__ float Xs[32][65]; // 65: conflict-free for both write (lane) and GEMM reads
  const int t = threadIdx.x;
  const int base = blockIdx.x * 32;  // NN % 32 == 0 -> no tail anywhere
  const int wv = t >> 6, lane = t & 63;
  const int nw = base + (wv << 4);   // this wave's first node

  int rsv = 0;
  if (lane < 17) rsv = rs[nw + lane];

  int beg = __shfl(rsv, 0);
  int deg = __shfl(rsv, 1) - beg;
  long long q = 0;
  if (lane < deg) q = __builtin_nontemporal_load(&csr[beg + lane]);

#pragma unroll 1
  for (int i = 0; i < 16; ++i) {
    // prefetch next node's packet (i==15: degN<=0 -> no load; values unused)
    int begN = __shfl(rsv, i + 1);
    int degN = __shfl(rsv, i + 2) - begN;
    long long qN = 0;
    if (lane < degN) qN = __builtin_nontemporal_load(&csr[begN + lane]);

    float a0 = 0.f, a1 = 0.f, a2 = 0.f, a3 = 0.f;
    const int dmain = min(deg, 64);
    int j = 0;
    for (; j + 7 < dmain; j += 8) {
      long long q0 = __shfl(q, j),     q1 = __shfl(q, j + 1);
      long long q2 = __shfl(q, j + 2), q3 = __shfl(q, j + 3);
      long long q4 = __shfl(q, j + 4), q5 = __shfl(q, j + 5);
      long long q6 = __shfl(q, j + 6), q7 = __shfl(q, j + 7);
      float v0 = xin[(int)q0 + lane], v1 = xin[(int)q1 + lane];
      float v2 = xin[(int)q2 + lane], v3 = xin[(int)q3 + lane];
      float v4 = xin[(int)q4 + lane], v5 = xin[(int)q5 + lane];
      float v6 = xin[(int)q6 + lane], v7 = xin[(int)q7 + lane];
      a0 = fmaf(v0, __int_as_float((int)(q0 >> 32)), a0);
      a1 = fmaf(v1, __int_as_float((int)(q1 >> 32)), a1);
      a2 = fmaf(v2, __int_as_float((int)(q2 >> 32)), a2);
      a3 = fmaf(v3, __int_as_float((int)(q3 >> 32)), a3);
      a0 = fmaf(v4, __int_as_float((int)(q4 >> 32)), a0);
      a1 = fmaf(v5, __int_as_float((int)(q5 >> 32)), a1);
      a2 = fmaf(v6, __int_as_float((int)(q6 >> 32)), a2);
      a3 = fmaf(v7, __int_as_float((int)(q7 >> 32)), a3);
    }
    for (; j + 3 < dmain; j += 4) {
      long long q0 = __shfl(q, j),     q1 = __shfl(q, j + 1);
      long long q2 = __shfl(q, j + 2), q3 = __shfl(q, j + 3);
      float v0 = xin[(int)q0 + lane], v1 = xin[(int)q1 + lane];
      float v2 = xin[(int)q2 + lane], v3 = xin[(int)q3 + lane];
      a0 = fmaf(v0, __int_as_float((int)(q0 >> 32)), a0);
      a1 = fmaf(v1, __int_as_float((int)(q1 >> 32)), a1);
      a2 = fmaf(v2, __int_as_float((int)(q2 >> 32)), a2);
      a3 = fmaf(v3, __int_as_float((int)(q3 >> 32)), a3);
    }
    for (; j < dmain; ++j) {
      long long q0 = __shfl(q, j);
      a0 = fmaf(xin[(int)q0 + lane], __int_as_float((int)(q0 >> 32)), a0);
    }
    for (int jj = 64; jj < deg; ++jj) { // rare: deg > 64 (uniform direct load)
      long long q0 = csr[beg + jj];
      a0 = fmaf(xin[(int)q0 + lane], __int_as_float((int)(q0 >> 32)), a0);
    }

    float r = scale * ((a0 + a1) + (a2 + a3));
    const int gn = nw + i;
    if (SUB) r -= __builtin_nontemporal_load(&sub[gn * 64 + lane]);
    Xs[(wv << 4) + i][lane] = r;
    if (WRITE_X) __builtin_nontemporal_store(r, &xout[gn * 64 + lane]);
    beg = begN; deg = degN; q = qN;
  }
  __syncthreads();

  const int j0 = (t & 15) << 2;  // output-dim group
  const int r0 = (t >> 4) << 2;  // node group (0..28)
  float acc4[4][4] = {};
#pragma unroll 8
  for (int d = 0; d < 64; ++d) {
    float4 wv4 = *(const float4*)&W[d * 64 + j0];
    float xv[4];
#pragma unroll
    for (int i = 0; i < 4; ++i) xv[i] = Xs[r0 + i][d];
#pragma unroll
    for (int i = 0; i < 4; ++i) {
      acc4[i][0] = fmaf(xv[i], wv4.x, acc4[i][0]);
      acc4[i][1] = fmaf(xv[i], wv4.y, acc4[i][1]);
      acc4[i][2] = fmaf(xv[i], wv4.z, acc4[i][2]);
      acc4[i][3] = fmaf(xv[i], wv4.w, acc4[i][3]);
    }
  }

#pragma unroll
  for (int i = 0; i < 4; ++i) {
    const int gn = base + r0 + i;
    f4_t* o = (f4_t*)&OUT[gn * 64 + j0];
    f4_t c = __builtin_nontemporal_load(o);
    f4_t r;
    if (MODE == 1) {
      r.x = acc4[i][0] + c.x; r.y = acc4[i][1] + c.y;
      r.z = acc4[i][2] + c.z; r.w = acc4[i][3] + c.w;
    } else {
      r.x = fmaxf(acc4[i][0] + c.x, 0.0f);
      r.y = fmaxf(acc4[i][1] + c.y, 0.0f);
      r.z = fmaxf(acc4[i][2] + c.z, 0.0f);
      r.w = fmaxf(acc4[i][3] + c.w, 0.0f);
    }
    __builtin_nontemporal_store(r, o);
  }
}

// ---------------- k=0 GEMM: ACC = X @ W + b (128 thr / 32 nodes, no tail) ----------------

__global__ __launch_bounds__(128) void gemm64_init(const float* __restrict__ X,
                                                   const float* __restrict__ W,
                                                   const float* __restrict__ bias,
                                                   float* __restrict__ OUT) {
  __shared__ float Xs[32][68];
  const int t = threadIdx.x;
  const int base = blockIdx.x * 32;

  const int nl = t >> 4;          // 0..7
  const int d4 = (t & 15) << 2;   // 0..60
#pragma unroll
  for (int i = 0; i < 4; ++i) {
    int n = nl + (i << 3);
    *(float4*)&Xs[n][d4] = *(const float4*)&X[(base + n) * 64 + d4];
  }
  __syncthreads();

  const int j0 = (t & 15) << 2;
  const int r0 = (t >> 4) << 2;
  float acc[4][4] = {};
#pragma unroll 8
  for (int d = 0; d < 64; ++d) {
    float4 wv = *(const float4*)&W[d * 64 + j0];
    float xv[4];
#pragma unroll
    for (int i = 0; i < 4; ++i) xv[i] = Xs[r0 + i][d];
#pragma unroll
    for (int i = 0; i < 4; ++i) {
      acc[i][0] = fmaf(xv[i], wv.x, acc[i][0]);
      acc[i][1] = fmaf(xv[i], wv.y, acc[i][1]);
      acc[i][2] = fmaf(xv[i], wv.z, acc[i][2]);
      acc[i][3] = fmaf(xv[i], wv.w, acc[i][3]);
    }
  }
  float4 b = *(const float4*)&bias[j0];
#pragma unroll
  for (int i = 0; i < 4; ++i) {
    float4 r;
    r.x = acc[i][0] + b.x; r.y = acc[i][1] + b.y;
    r.z = acc[i][2] + b.z; r.w = acc[i][3] + b.w;
    *(float4*)&OUT[(base + r0 + i) * 64 + j0] = r;
  }
}

// ---------------- pooling ----------------

__device__ __forceinline__ unsigned enc_f32(float f) {
  unsigned u = __float_as_uint(f);
  return (u & 0x80000000u) ? ~u : (u | 0x80000000u);
}
__device__ __forceinline__ float dec_f32(unsigned v) {
  return (v & 0x80000000u) ? __uint_as_float(v ^ 0x80000000u) : __uint_as_float(~v);
}

__global__ void gate_kernel(const float* __restrict__ h, const float* __restrict__ Wg,
                            const float* __restrict__ bg, const int* __restrict__ seg,
                            float* __restrict__ gate, unsigned* __restrict__ gmax) {
  __shared__ float wg_s[64];
  __shared__ unsigned gmax_l[NG];
  int t = threadIdx.x;
  if (t < 64) wg_s[t] = Wg[t];
  if (t < NG) gmax_l[t] = 0u;
  __syncthreads();
  int n = blockIdx.x * 256 + t;
  if (n < NN) {
    float acc = bg[0];
    const float4* hx = (const float4*)&h[n * 64];
#pragma unroll
    for (int d4 = 0; d4 < 16; ++d4) {
      float4 v = hx[d4];
      acc += v.x * wg_s[d4 * 4] + v.y * wg_s[d4 * 4 + 1] +
             v.z * wg_s[d4 * 4 + 2] + v.w * wg_s[d4 * 4 + 3];
    }
    gate[n] = acc;
    atomicMax(&gmax_l[seg[n]], enc_f32(acc));
  }
  __syncthreads();
  if (t < NG && gmax_l[t]) atomicMax(&gmax[t], gmax_l[t]);
}

__global__ void ek_kernel(float* __restrict__ gate, const int* __restrict__ seg,
                          const unsigned* __restrict__ gmax, float* __restrict__ z) {
  __shared__ float zl[NG];
  int t = threadIdx.x;
  if (t < NG) zl[t] = 0.0f;
  __syncthreads();
  int n = blockIdx.x * 256 + t;
  if (n < NN) {
    int g = seg[n];
    float e = expf(gate[n] - dec_f32(gmax[g]));
    gate[n] = e;
    atomicAdd(&zl[g], e);
  }
  __syncthreads();
  if (t < NG && zl[t] != 0.0f) atomicAdd(&z[t], zl[t]);
}

constexpr int CHUNKS = 1024;
constexpr int CHUNK_LEN = (NN + CHUNKS - 1) / CHUNKS; // 98

__global__ void hg_kernel(const float* __restrict__ h, const float* __restrict__ e,
                          const int* __restrict__ seg, const float* __restrict__ z,
                          float* __restrict__ hg) {
  int t = threadIdx.x;
  int d = t & 63;
  int chunk = blockIdx.x * 4 + (t >> 6);
  int n0 = chunk * CHUNK_LEN;
  if (n0 >= NN) return;
  int n1 = min(n0 + CHUNK_LEN, NN);
  float acc = 0.0f;
  int gc = seg[n0];
  for (int n = n0; n < n1; ++n) {
    int g = seg[n];
    if (g != gc) {
      atomicAdd(&hg[gc * 64 + d], acc / z[gc]);
      acc = 0.0f;
      gc = g;
    }
    acc = fmaf(h[n * 64 + d], e[n], acc);
  }
  atomicAdd(&hg[gc * 64 + d], acc / z[gc]);
}

__global__ void final_kernel(const float* __restrict__ hg, const float* __restrict__ W1,
                             const float* __restrict__ b1, const float* __restrict__ W2,
                             const float* __restrict__ b2, float* __restrict__ out) {
  __shared__ float hgs[NG][64];
  __shared__ float a2[NG][64];
  int t = threadIdx.x;
  for (int i = t; i < NG * 64; i += 256) hgs[i >> 6][i & 63] = hg[i];
  __syncthreads();
  int j = t & 63;
  int g0 = t >> 6; // 0..3
#pragma unroll
  for (int i = 0; i < 4; ++i) {
    int g = g0 * 4 + i;
    float acc = b1[j];
    for (int d = 0; d < 64; ++d) acc = fmaf(hgs[g][d], W1[d * 64 + j], acc);
    a2[g][j] = acc; // no relu (matches reference)
  }
  __syncthreads();
  if (t < NG * NCLASSES) {
    int g = t / NCLASSES, c = t % NCLASSES;
    float acc = b2[c];
    for (int d = 0; d < 64; ++d) acc = fmaf(a2[g][d], W2[d * NCLASSES + c], acc);
    out[g * NCLASSES + c] = acc;
  }
}

// ---------------- host ----------------

extern "C" void kernel_launch(void* const* d_in, const int* in_sizes, int n_in,
                              void* d_out, int out_size, void* d_ws, size_t ws_size,
                              hipStream_t stream) {
  const float* feat = (const float*)d_in[0];
  const float* Wc   = (const float*)d_in[1];
  const float* bc   = (const float*)d_in[2];
  const float* Wg   = (const float*)d_in[3];
  const float* bg   = (const float*)d_in[4];
  const float* W1   = (const float*)d_in[5];
  const float* b1   = (const float*)d_in[6];
  const float* W2   = (const float*)d_in[7];
  const float* b2   = (const float*)d_in[8];
  const int*   src  = (const int*)d_in[9];
  const int*   dst  = (const int*)d_in[10];
  const int*   seg  = (const int*)d_in[11];
  float* out = (float*)d_out;

  // workspace carve (4B units; all major buffers 16B-aligned by construction)
  float* fw = (float*)d_ws;
  size_t off = 0;
  float* w0 = fw + off; off += (size_t)NN * 64;   // 6.4M
  float* w1 = fw + off; off += (size_t)NN * 64;
  float* w2 = fw + off; off += (size_t)NN * 64;
  float* nrm  = fw + off; off += NN;
  float* gate = fw + off; off += NN;
  float* zbuf = fw + off; off += 16;
  unsigned* gmax = (unsigned*)(fw + off); off += 16;
  float* hg = fw + off; off += NG * 64;
  // off*4 is a multiple of 16 here -> csr is 8B-aligned
  long long* csr = (long long*)(fw + off); off += (size_t)NE * 2;
  int* deg     = (int*)(fw + off);
  int* cursor  = deg + NN;
  int* rs      = cursor + NN;
  int* partial = rs + NN + 1;
  size_t need = (off + 2 * (size_t)NN + (NN + 1) + (NTILES + 1)) * 4;
  if (ws_size < need) return; // insufficient workspace -> loud validation failure

  hipMemsetAsync(deg, 0, NN * sizeof(int), stream);
  hipMemsetAsync(cursor, 0, NN * sizeof(int), stream);
  hipMemsetAsync(gmax, 0, NG * sizeof(unsigned), stream);
  hipMemsetAsync(zbuf, 0, NG * sizeof(float), stream);
  hipMemsetAsync(hg, 0, NG * 64 * sizeof(float), stream);

  degree_kernel<<<(NE + 255) / 256, 256, 0, stream>>>(dst, deg);
  norm_kernel<<<(NN + 255) / 256, 256, 0, stream>>>(deg, nrm);
  tile_reduce<<<NTILES, SCAN_TILE, 0, stream>>>(deg, partial);
  scan_partials<<<1, 64, 0, stream>>>(partial, rs);
  tile_scan<<<NTILES, SCAN_TILE, 0, stream>>>(deg, partial, rs);
  fill_kernel<<<(NE + 255) / 256, 256, 0, stream>>>(src, dst, rs, nrm, cursor,
                                                    (int2*)csr);

  const int GB = NN / 32; // 3125 blocks, no tail

  // Buffer plan (3 node buffers + read-only feat):
  //  L0: x0=feat, A=w0, B=w1, acc=w2 -> h=w2
  //  L1: x0=w2,   A=w0, B=w2, acc=w1 -> h=w1
  //  L2: x0=w1,   A=w0, B=w1, acc=w2 -> h=w2
  //  L3: x0=w2,   A=w0, B=w2, acc=w1 -> h=w1
  const float* h = feat;
  for (int layer = 0; layer < NLAYERS; ++layer) {
    const float* Wl = Wc + (size_t)layer * KORD * 64 * 64;
    const float* bl = bc + (size_t)layer * 64;
    const float* x0 = h;
    float* A = w0;
    float* B = (layer == 0) ? w1 : (float*)x0;           // X2 overwrites h_in (elem-wise)
    float* acc = (layer == 0) ? w2 : ((x0 == w2) ? w1 : w2);

    // k=0: acc = X0 @ W0 + b
    gemm64_init<<<GB, 128, 0, stream>>>(x0, Wl, bl, acc);
    // k=1: X1 = -A_hat X0 ; acc += X1 @ W1
    prop_gemm<1, false, true><<<GB, 128, 0, stream>>>(x0, nullptr, rs, csr,
                                                      Wl + 4096, A, acc, -1.0f);
    // k=2: X2 = -2 A_hat X1 - X0 ; acc += X2 @ W2
    prop_gemm<1, true, true><<<GB, 128, 0, stream>>>(A, x0, rs, csr,
                                                     Wl + 2 * 4096, B, acc, -2.0f);
    // k=3..K-1: X_k = -2 A_hat X_{k-1} - X_{k-2}, overwrite X_{k-2} in place
    float* p = A; // X_{k-2}
    float* q = B; // X_{k-1}
    for (int k = 3; k < KORD; ++k) {
      if (k == KORD - 1) {
        prop_gemm<2, true, false><<<GB, 128, 0, stream>>>(q, p, rs, csr,
                                                          Wl + (size_t)k * 4096, p, acc, -2.0f);
      } else {
        prop_gemm<1, true, true><<<GB, 128, 0, stream>>>(q, p, rs, csr,
                                                         Wl + (size_t)k * 4096, p, acc, -2.0f);
        float* tmp = p; p = q; q = tmp;
      }
    }
    h = acc; // relu applied in the last prop_gemm (MODE 2)
  }

  gate_kernel<<<(NN + 255) / 256, 256, 0, stream>>>(h, Wg, bg, seg, gate, gmax);
  ek_kernel<<<(NN + 255) / 256, 256, 0, stream>>>(gate, seg, gmax, zbuf);
  hg_kernel<<<256, 256, 0, stream>>>(h, gate, seg, zbuf, hg);
  final_kernel<<<1, 256, 0, stream>>>(hg, W1, b1, W2, b2, out);
}